// Round 1
// baseline (907.533 us; speedup 1.0000x reference)
//
#include <hip/hip_runtime.h>
#include <hip/hip_bf16.h>

// Problem dims (fixed by reference)
#define BATCH 16384
#define TT    64
#define INF   48
#define FF    32
#define TFD   2048   // T*F   (GEMM K)
#define THD   8192   // T*H   (GEMM N)

typedef __attribute__((ext_vector_type(8))) short bf16x8;
typedef __attribute__((ext_vector_type(4))) float f32x4;

__device__ inline void gload_lds16(const void* g, void* l) {
  __builtin_amdgcn_global_load_lds((const __attribute__((address_space(1))) void*)g,
                                   (__attribute__((address_space(3))) void*)l, 16, 0, 0);
}

// ---------------- prep kernels ----------------

// xs[b][t*32+f] = bf16(x[b][t*48 + sidx[f]])
__global__ void gather_cast(const float* __restrict__ x, const int* __restrict__ sidx,
                            __hip_bfloat16* __restrict__ xs) {
  const int b = blockIdx.x;
  const float* xr = x + (size_t)b * TT * INF;
  __hip_bfloat16* o = xs + (size_t)b * TFD;
  for (int j = threadIdx.x; j < TFD; j += 256) {
    const int t = j >> 5, f = j & 31;
    o[j] = __float2bfloat16(xr[t * INF + sidx[f]]);
  }
}

// W1t[n][k] = bf16(W1[k][n]);  W1: [TFD][THD] row-major
__global__ void transpose_w1(const float* __restrict__ W1, __hip_bfloat16* __restrict__ W1t) {
  __shared__ float tile[64][65];
  const int k0 = blockIdx.x * 64;   // 2048/64 = 32
  const int n0 = blockIdx.y * 64;   // 8192/64 = 128
  const int tx = threadIdx.x & 63, ty = threadIdx.x >> 6;
  for (int r = ty; r < 64; r += 4)
    tile[r][tx] = W1[(size_t)(k0 + r) * THD + n0 + tx];
  __syncthreads();
  for (int r = ty; r < 64; r += 4)
    W1t[(size_t)(n0 + r) * TFD + k0 + tx] = __float2bfloat16(tile[tx][r]);
}

// W2eff[n][f] = sum_t W2[n][t*32+f]*weight[t][f];  beff[f] = bias[f] + sum_t b2[t*32+f]*weight[t][f]
__global__ void make_w2eff(const float* __restrict__ W2, const float* __restrict__ b2,
                           const float* __restrict__ weight, const float* __restrict__ bias,
                           float* __restrict__ W2eff, float* __restrict__ beff) {
  const int n = blockIdx.x * 8 + (threadIdx.x >> 5);
  const int f = threadIdx.x & 31;
  const float* wr = W2 + (size_t)n * TFD;
  float s = 0.f;
  #pragma unroll 8
  for (int t = 0; t < TT; ++t) s += wr[t * FF + f] * weight[t * FF + f];
  W2eff[n * FF + f] = s;
  if (blockIdx.x == 0 && threadIdx.x < FF) {
    float sb = bias[f];
    for (int t = 0; t < TT; ++t) sb += b2[t * FF + f] * weight[t * FF + f];
    beff[f] = sb;
  }
}

// ---------------- main fused GEMM ----------------
// C tile 128x128 bf16 MFMA, BK=64, double-buffered global_load_lds staging.
// Each block handles one 128-row batch panel x one strip of 8 N-tiles,
// fusing h = relu(xs@W1+b1) with partial[b,f] += h_tile @ W2eff[tile].

__device__ inline void stage(const __hip_bfloat16* __restrict__ xs,
                             const __hip_bfloat16* __restrict__ w1t,
                             char* buf, int b0, int n0, int k0, int w, int l) {
  char* ldsA = buf;
  char* ldsB = buf + 16384;
  const char* ga = (const char*)(xs  + (size_t)b0 * TFD + k0) + (size_t)(l >> 3) * (TFD * 2) + (l & 7) * 16;
  const char* gb = (const char*)(w1t + (size_t)n0 * TFD + k0) + (size_t)(l >> 3) * (TFD * 2) + (l & 7) * 16;
  #pragma unroll
  for (int r = 0; r < 4; ++r) {
    const int s = r * 4 + w;                      // segment: 8 rows of 128B = 1KB
    gload_lds16(ga + (size_t)s * 8 * TFD * 2, ldsA + s * 1024);
    gload_lds16(gb + (size_t)s * 8 * TFD * 2, ldsB + s * 1024);
  }
}

__global__ __launch_bounds__(256, 2) void gemm_fused(
    const __hip_bfloat16* __restrict__ xs,    // [BATCH][TFD]
    const __hip_bfloat16* __restrict__ w1t,   // [THD][TFD]
    const float* __restrict__ b1,             // [THD]
    const float* __restrict__ w2eff,          // [THD][FF]
    float* __restrict__ partial)              // [8][BATCH][FF]
{
  __shared__ __align__(16) char lds[65536];   // 2 x (A 16KB + B 16KB)
  const int tid = threadIdx.x;
  const int w = tid >> 6, l = tid & 63;
  const int wr = w >> 1, wc = w & 1;          // wave quadrant (64x64)
  const int b0 = blockIdx.x * 128;
  const int strip = blockIdx.y;               // 0..7
  const int rr = tid >> 1, fg = tid & 1;      // epilogue roles

  float acc2[16];
  #pragma unroll
  for (int i = 0; i < 16; ++i) acc2[i] = 0.f;

  for (int nt = 0; nt < 8; ++nt) {
    const int n0 = strip * 1024 + nt * 128;

    f32x4 acc[4][4];
    #pragma unroll
    for (int m = 0; m < 4; ++m)
      #pragma unroll
      for (int n = 0; n < 4; ++n) { f32x4 z = {0.f, 0.f, 0.f, 0.f}; acc[m][n] = z; }

    stage(xs, w1t, lds, b0, n0, 0, w, l);
    __syncthreads();

    for (int kt = 0; kt < TFD / 64; ++kt) {
      const char* cur = lds + (size_t)(kt & 1) * 32768;
      if (kt < TFD / 64 - 1)
        stage(xs, w1t, lds + (size_t)((kt + 1) & 1) * 32768, b0, n0, (kt + 1) * 64, w, l);

      const char* A  = cur;            // [128][64] bf16, 128B rows
      const char* Bt = cur + 16384;    // [128][64] bf16 (N-major)
      #pragma unroll
      for (int kk = 0; kk < 2; ++kk) {
        bf16x8 a[4], b[4];
        const int ko = kk * 64 + ((l >> 4) << 4);   // k = kk*32 + (l>>4)*8, bytes
        #pragma unroll
        for (int m = 0; m < 4; ++m)
          a[m] = *(const bf16x8*)(A + (wr * 64 + m * 16 + (l & 15)) * 128 + ko);
        #pragma unroll
        for (int n = 0; n < 4; ++n)
          b[n] = *(const bf16x8*)(Bt + (wc * 64 + n * 16 + (l & 15)) * 128 + ko);
        #pragma unroll
        for (int m = 0; m < 4; ++m)
          #pragma unroll
          for (int n = 0; n < 4; ++n)
            acc[m][n] = __builtin_amdgcn_mfma_f32_16x16x32_bf16(a[m], b[n], acc[m][n], 0, 0, 0);
      }
      __syncthreads();
    }

    // ---- epilogue: bias+relu, h tile -> LDS (bf16), contract with W2eff chunk ----
    __hip_bfloat16* h_lds = (__hip_bfloat16*)lds;     // [128][132] (pad kills bank conflict)
    float* w2_lds = (float*)(lds + 40960);            // [128][32]

    float biasv[4];
    #pragma unroll
    for (int n = 0; n < 4; ++n) biasv[n] = b1[n0 + wc * 64 + n * 16 + (l & 15)];

    #pragma unroll
    for (int m = 0; m < 4; ++m) {
      const int r0 = wr * 64 + m * 16 + ((l >> 4) << 2);
      #pragma unroll
      for (int n = 0; n < 4; ++n) {
        const int c = wc * 64 + n * 16 + (l & 15);
        #pragma unroll
        for (int j = 0; j < 4; ++j) {
          float hv = acc[m][n][j] + biasv[n];
          hv = hv > 0.f ? hv : 0.f;
          h_lds[(r0 + j) * 132 + c] = __float2bfloat16(hv);
        }
      }
    }
    {
      const float4* src = (const float4*)(w2eff + (size_t)n0 * FF);
      float4* dst = (float4*)w2_lds;
      for (int i = tid; i < 1024; i += 256) dst[i] = src[i];
    }
    __syncthreads();

    const float* wbase = w2_lds + fg * 16;
    #pragma unroll 4
    for (int j = 0; j < 128; ++j) {
      const float hv = __bfloat162float(h_lds[rr * 132 + j]);
      const float* wrow = wbase + j * 32;
      #pragma unroll
      for (int i = 0; i < 16; ++i) acc2[i] += hv * wrow[i];
    }
    __syncthreads();   // protect LDS before next nt's staging
  }

  float* pout = partial + ((size_t)strip * BATCH + b0 + rr) * FF + fg * 16;
  #pragma unroll
  for (int i = 0; i < 16; ++i) pout[i] = acc2[i];
}

// out[b][f] = beff[f] + sum_c partial[c][b][f]
__global__ void reduce_partial(const float* __restrict__ partial, const float* __restrict__ beff,
                               float* __restrict__ out) {
  const int idx = blockIdx.x * 256 + threadIdx.x;
  float s = beff[idx & 31];
  #pragma unroll
  for (int c = 0; c < 8; ++c) s += partial[(size_t)c * BATCH * FF + idx];
  out[idx] = s;
}

// ---------------- launch ----------------

extern "C" void kernel_launch(void* const* d_in, const int* in_sizes, int n_in,
                              void* d_out, int out_size, void* d_ws, size_t ws_size,
                              hipStream_t stream) {
  const float* x      = (const float*)d_in[0];
  const float* W1     = (const float*)d_in[1];
  const float* b1     = (const float*)d_in[2];
  const float* W2     = (const float*)d_in[3];
  const float* b2     = (const float*)d_in[4];
  const float* weight = (const float*)d_in[5];
  const float* bias   = (const float*)d_in[6];
  const int*   sidx   = (const int*)d_in[7];

  char* ws = (char*)d_ws;
  // ws layout (bytes):
  //   xs      [16384][2048] bf16 :         0 ..  67108864
  //   w1t     [8192][2048]  bf16 :  67108864 .. 100663296
  //   w2eff   [8192][32]    f32  : 100663296 .. 101711872
  //   beff    [32]          f32  : 101711872 .. 101712000
  //   partial [8][16384][32] f32 : 101712384 .. 118489600   (needs ws >= ~119MB)
  __hip_bfloat16* xs    = (__hip_bfloat16*)ws;
  __hip_bfloat16* w1t   = (__hip_bfloat16*)(ws + 67108864);
  float*          w2eff = (float*)(ws + 100663296);
  float*          beff  = (float*)(ws + 101711872);
  float*          part  = (float*)(ws + 101712384);

  hipLaunchKernelGGL(gather_cast,  dim3(BATCH),   dim3(256), 0, stream, x, sidx, xs);
  hipLaunchKernelGGL(transpose_w1, dim3(32, 128), dim3(256), 0, stream, W1, w1t);
  hipLaunchKernelGGL(make_w2eff,   dim3(1024),    dim3(256), 0, stream, W2, b2, weight, bias, w2eff, beff);
  hipLaunchKernelGGL(gemm_fused,   dim3(128, 8),  dim3(256), 0, stream, xs, w1t, b1, w2eff, part);
  hipLaunchKernelGGL(reduce_partial, dim3(2048),  dim3(256), 0, stream, part, beff, (float*)d_out);
}

// Round 2
// 767.800 us; speedup vs baseline: 1.1820x; 1.1820x over previous
//
#include <hip/hip_runtime.h>
#include <hip/hip_bf16.h>

// Problem dims (fixed by reference)
#define BATCH 16384
#define TT    64
#define INF   48
#define FF    32
#define TFD   2048   // T*F   (GEMM K)
#define THD   8192   // T*H   (GEMM N)

typedef __attribute__((ext_vector_type(8))) short bf16x8;
typedef __attribute__((ext_vector_type(4))) float f32x4;

__device__ inline void gload_lds16(const void* g, void* l) {
  __builtin_amdgcn_global_load_lds((const __attribute__((address_space(1))) void*)g,
                                   (__attribute__((address_space(3))) void*)l, 16, 0, 0);
}

// ---------------- prep kernels ----------------

// xs[b][t*32+f] = bf16(x[b][t*48 + sidx[f]])
__global__ void gather_cast(const float* __restrict__ x, const int* __restrict__ sidx,
                            __hip_bfloat16* __restrict__ xs) {
  const int b = blockIdx.x;
  const float* xr = x + (size_t)b * TT * INF;
  __hip_bfloat16* o = xs + (size_t)b * TFD;
  for (int j = threadIdx.x; j < TFD; j += 256) {
    const int t = j >> 5, f = j & 31;
    o[j] = __float2bfloat16(xr[t * INF + sidx[f]]);
  }
}

// W1t[n][k] = bf16(W1[k][n]);  W1: [TFD][THD] row-major
__global__ void transpose_w1(const float* __restrict__ W1, __hip_bfloat16* __restrict__ W1t) {
  __shared__ float tile[64][65];
  const int k0 = blockIdx.x * 64;   // 2048/64 = 32
  const int n0 = blockIdx.y * 64;   // 8192/64 = 128
  const int tx = threadIdx.x & 63, ty = threadIdx.x >> 6;
  for (int r = ty; r < 64; r += 4)
    tile[r][tx] = W1[(size_t)(k0 + r) * THD + n0 + tx];
  __syncthreads();
  for (int r = ty; r < 64; r += 4)
    W1t[(size_t)(n0 + r) * TFD + k0 + tx] = __float2bfloat16(tile[tx][r]);
}

// W2eff[n][f] = sum_t W2[n][t*32+f]*weight[t][f];  beff[f] = bias[f] + sum_t b2[t*32+f]*weight[t][f]
__global__ void make_w2eff(const float* __restrict__ W2, const float* __restrict__ b2,
                           const float* __restrict__ weight, const float* __restrict__ bias,
                           float* __restrict__ W2eff, float* __restrict__ beff) {
  const int n = blockIdx.x * 8 + (threadIdx.x >> 5);
  const int f = threadIdx.x & 31;
  const float* wr = W2 + (size_t)n * TFD;
  float s = 0.f;
  #pragma unroll 8
  for (int t = 0; t < TT; ++t) s += wr[t * FF + f] * weight[t * FF + f];
  W2eff[n * FF + f] = s;
  if (blockIdx.x == 0 && threadIdx.x < FF) {
    float sb = bias[f];
    for (int t = 0; t < TT; ++t) sb += b2[t * FF + f] * weight[t * FF + f];
    beff[f] = sb;
  }
}

// ---------------- main fused GEMM ----------------
// C tile 128x128 bf16 MFMA, BK=64, double-buffered global_load_lds staging.
// LDS tiles are XOR-swizzled (byte ^= (row&7)<<4) to kill the 32-bank-stride
// conflict on the MFMA fragment ds_read_b128s. Since global_load_lds writes
// linearly (base + lane*16), the swizzle is applied by PRE-SWIZZLING the
// global source column per lane (rule: linear dest + inverse-swz source +
// swz on read).

__device__ inline void stage(const __hip_bfloat16* __restrict__ xs,
                             const __hip_bfloat16* __restrict__ w1t,
                             char* buf, int b0, int n0, int k0, int w, int l) {
  char* ldsA = buf;
  char* ldsB = buf + 16384;
  // lane l covers row (l>>3) of its 8-row segment; the 16B chunk that must
  // land at LDS slot (l&7) is global column16 (l&7) ^ (row&7).
  const int c16 = ((l & 7) ^ ((l >> 3) & 7)) * 16;
  const char* ga = (const char*)(xs  + (size_t)b0 * TFD + k0) + (size_t)(l >> 3) * (TFD * 2) + c16;
  const char* gb = (const char*)(w1t + (size_t)n0 * TFD + k0) + (size_t)(l >> 3) * (TFD * 2) + c16;
  #pragma unroll
  for (int r = 0; r < 4; ++r) {
    const int s = r * 4 + w;                      // segment: 8 rows of 128B = 1KB
    gload_lds16(ga + (size_t)s * 8 * TFD * 2, ldsA + s * 1024);
    gload_lds16(gb + (size_t)s * 8 * TFD * 2, ldsB + s * 1024);
  }
}

__global__ __launch_bounds__(256, 2) void gemm_fused(
    const __hip_bfloat16* __restrict__ xs,    // [BATCH][TFD]
    const __hip_bfloat16* __restrict__ w1t,   // [THD][TFD]
    const float* __restrict__ b1,             // [THD]
    const float* __restrict__ w2eff,          // [THD][FF]
    float* __restrict__ partial)              // [8][BATCH][FF]
{
  __shared__ __align__(16) char lds[65536];   // 2 x (A 16KB + B 16KB)
  const int tid = threadIdx.x;
  const int w = tid >> 6, l = tid & 63;
  const int wr = w >> 1, wc = w & 1;          // wave quadrant (64x64)
  const int b0 = blockIdx.x * 128;
  const int strip = blockIdx.y;               // 0..7
  const int rr = tid >> 1, fg = tid & 1;      // epilogue roles
  const int swz = (l & 7) << 4;               // read-side XOR (row&7 == l&7 for all frags)

  float acc2[16];
  #pragma unroll
  for (int i = 0; i < 16; ++i) acc2[i] = 0.f;

  for (int nt = 0; nt < 8; ++nt) {
    const int n0 = strip * 1024 + nt * 128;

    f32x4 acc[4][4];
    #pragma unroll
    for (int m = 0; m < 4; ++m)
      #pragma unroll
      for (int n = 0; n < 4; ++n) { f32x4 z = {0.f, 0.f, 0.f, 0.f}; acc[m][n] = z; }

    stage(xs, w1t, lds, b0, n0, 0, w, l);
    __syncthreads();

    for (int kt = 0; kt < TFD / 64; ++kt) {
      const char* cur = lds + (size_t)(kt & 1) * 32768;
      if (kt < TFD / 64 - 1)
        stage(xs, w1t, lds + (size_t)((kt + 1) & 1) * 32768, b0, n0, (kt + 1) * 64, w, l);

      const char* A  = cur;            // [128][64] bf16, swizzled 128B rows
      const char* Bt = cur + 16384;    // [128][64] bf16 (N-major), swizzled
      #pragma unroll
      for (int kk = 0; kk < 2; ++kk) {
        bf16x8 a[4], b[4];
        const int ko = (kk * 64 + ((l >> 4) << 4)) ^ swz;   // swizzled k-byte
        #pragma unroll
        for (int m = 0; m < 4; ++m)
          a[m] = *(const bf16x8*)(A + (wr * 64 + m * 16 + (l & 15)) * 128 + ko);
        #pragma unroll
        for (int n = 0; n < 4; ++n)
          b[n] = *(const bf16x8*)(Bt + (wc * 64 + n * 16 + (l & 15)) * 128 + ko);
        #pragma unroll
        for (int m = 0; m < 4; ++m)
          #pragma unroll
          for (int n = 0; n < 4; ++n)
            acc[m][n] = __builtin_amdgcn_mfma_f32_16x16x32_bf16(a[m], b[n], acc[m][n], 0, 0, 0);
      }
      __syncthreads();
    }

    // ---- epilogue: bias+relu, h tile -> LDS (bf16), contract with W2eff chunk ----
    __hip_bfloat16* h_lds = (__hip_bfloat16*)lds;     // [128][136] (pad: 272B row, 16B-aligned)
    float* w2_lds = (float*)(lds + 40960);            // [128][32]

    float biasv[4];
    #pragma unroll
    for (int n = 0; n < 4; ++n) biasv[n] = b1[n0 + wc * 64 + n * 16 + (l & 15)];

    #pragma unroll
    for (int m = 0; m < 4; ++m) {
      const int r0 = wr * 64 + m * 16 + ((l >> 4) << 2);
      #pragma unroll
      for (int n = 0; n < 4; ++n) {
        const int c = wc * 64 + n * 16 + (l & 15);
        #pragma unroll
        for (int j = 0; j < 4; ++j) {
          float hv = acc[m][n][j] + biasv[n];
          hv = hv > 0.f ? hv : 0.f;
          h_lds[(r0 + j) * 136 + c] = __float2bfloat16(hv);
        }
      }
    }
    {
      const float4* src = (const float4*)(w2eff + (size_t)n0 * FF);
      float4* dst = (float4*)w2_lds;
      for (int i = tid; i < 1024; i += 256) dst[i] = src[i];
    }
    __syncthreads();

    // vectorized contraction: h row as bf16x8 b128 reads, w2 as broadcast float4
    const __hip_bfloat16* h_base = h_lds + rr * 136;
    const float* wbase = w2_lds + fg * 16;
    #pragma unroll 2
    for (int j8 = 0; j8 < 16; ++j8) {
      const bf16x8 hv8 = *(const bf16x8*)(h_base + j8 * 8);
      #pragma unroll
      for (int jj = 0; jj < 8; ++jj) {
        const unsigned u = ((unsigned)(unsigned short)hv8[jj]) << 16;
        const float hv = __builtin_bit_cast(float, u);
        const float4* wrow = (const float4*)(wbase + (j8 * 8 + jj) * 32);
        const float4 w0 = wrow[0], w1v = wrow[1], w2v = wrow[2], w3v = wrow[3];
        acc2[0]  += hv * w0.x;  acc2[1]  += hv * w0.y;  acc2[2]  += hv * w0.z;  acc2[3]  += hv * w0.w;
        acc2[4]  += hv * w1v.x; acc2[5]  += hv * w1v.y; acc2[6]  += hv * w1v.z; acc2[7]  += hv * w1v.w;
        acc2[8]  += hv * w2v.x; acc2[9]  += hv * w2v.y; acc2[10] += hv * w2v.z; acc2[11] += hv * w2v.w;
        acc2[12] += hv * w3v.x; acc2[13] += hv * w3v.y; acc2[14] += hv * w3v.z; acc2[15] += hv * w3v.w;
      }
    }
    __syncthreads();   // protect LDS before next nt's staging
  }

  float* pout = partial + ((size_t)strip * BATCH + b0 + rr) * FF + fg * 16;
  #pragma unroll
  for (int i = 0; i < 16; ++i) pout[i] = acc2[i];
}

// out[b][f] = beff[f] + sum_c partial[c][b][f]
__global__ void reduce_partial(const float* __restrict__ partial, const float* __restrict__ beff,
                               float* __restrict__ out) {
  const int idx = blockIdx.x * 256 + threadIdx.x;
  float s = beff[idx & 31];
  #pragma unroll
  for (int c = 0; c < 8; ++c) s += partial[(size_t)c * BATCH * FF + idx];
  out[idx] = s;
}

// ---------------- launch ----------------

extern "C" void kernel_launch(void* const* d_in, const int* in_sizes, int n_in,
                              void* d_out, int out_size, void* d_ws, size_t ws_size,
                              hipStream_t stream) {
  const float* x      = (const float*)d_in[0];
  const float* W1     = (const float*)d_in[1];
  const float* b1     = (const float*)d_in[2];
  const float* W2     = (const float*)d_in[3];
  const float* b2     = (const float*)d_in[4];
  const float* weight = (const float*)d_in[5];
  const float* bias   = (const float*)d_in[6];
  const int*   sidx   = (const int*)d_in[7];

  char* ws = (char*)d_ws;
  // ws layout (bytes):
  //   xs      [16384][2048] bf16 :         0 ..  67108864
  //   w1t     [8192][2048]  bf16 :  67108864 .. 100663296
  //   w2eff   [8192][32]    f32  : 100663296 .. 101711872
  //   beff    [32]          f32  : 101711872 .. 101712000
  //   partial [8][16384][32] f32 : 101712384 .. 118489600
  __hip_bfloat16* xs    = (__hip_bfloat16*)ws;
  __hip_bfloat16* w1t   = (__hip_bfloat16*)(ws + 67108864);
  float*          w2eff = (float*)(ws + 100663296);
  float*          beff  = (float*)(ws + 101711872);
  float*          part  = (float*)(ws + 101712384);

  hipLaunchKernelGGL(gather_cast,  dim3(BATCH),   dim3(256), 0, stream, x, sidx, xs);
  hipLaunchKernelGGL(transpose_w1, dim3(32, 128), dim3(256), 0, stream, W1, w1t);
  hipLaunchKernelGGL(make_w2eff,   dim3(1024),    dim3(256), 0, stream, W2, b2, weight, bias, w2eff, beff);
  hipLaunchKernelGGL(gemm_fused,   dim3(128, 8),  dim3(256), 0, stream, xs, w1t, b1, w2eff, part);
  hipLaunchKernelGGL(reduce_partial, dim3(2048),  dim3(256), 0, stream, part, beff, (float*)d_out);
}

// Round 3
// 640.564 us; speedup vs baseline: 1.4168x; 1.1986x over previous
//
#include <hip/hip_runtime.h>
#include <hip/hip_bf16.h>

// Problem dims (fixed by reference)
#define BATCH 16384
#define TT    64
#define INF   48
#define FF    32
#define TFD   2048   // T*F   (GEMM1 K)
#define THD   8192   // T*H   (GEMM1 N)

typedef __attribute__((ext_vector_type(8))) short bf16x8;
typedef __attribute__((ext_vector_type(4))) short bf16x4;
typedef __attribute__((ext_vector_type(4))) float f32x4;

__device__ inline void gload_lds16(const void* g, void* l) {
  __builtin_amdgcn_global_load_lds((const __attribute__((address_space(1))) void*)g,
                                   (__attribute__((address_space(3))) void*)l, 16, 0, 0);
}

__device__ inline f32x4 mfma16x16x16_bf16(bf16x4 a, bf16x4 b, f32x4 c) {
#if __has_builtin(__builtin_amdgcn_mfma_f32_16x16x16bf16_1k)
  return __builtin_amdgcn_mfma_f32_16x16x16bf16_1k(a, b, c, 0, 0, 0);
#else
  asm("v_mfma_f32_16x16x16_bf16 %0, %1, %2, %0" : "+v"(c) : "v"(a), "v"(b));
  return c;
#endif
}

__device__ inline short f32_to_bf16_bits(float x) {
  __hip_bfloat16 h = __float2bfloat16(x);
  return *reinterpret_cast<short*>(&h);
}

// ---------------- prep kernels ----------------

// xs[b][t*32+f] = bf16(x[b][t*48 + sidx[f]])
__global__ void gather_cast(const float* __restrict__ x, const int* __restrict__ sidx,
                            __hip_bfloat16* __restrict__ xs) {
  const int b = blockIdx.x;
  const float* xr = x + (size_t)b * TT * INF;
  __hip_bfloat16* o = xs + (size_t)b * TFD;
  for (int j = threadIdx.x; j < TFD; j += 256) {
    const int t = j >> 5, f = j & 31;
    o[j] = __float2bfloat16(xr[t * INF + sidx[f]]);
  }
}

// W1t[n][k] = bf16(W1[k][n]);  W1: [TFD][THD] row-major
__global__ void transpose_w1(const float* __restrict__ W1, __hip_bfloat16* __restrict__ W1t) {
  __shared__ float tile[64][65];
  const int k0 = blockIdx.x * 64;
  const int n0 = blockIdx.y * 64;
  const int tx = threadIdx.x & 63, ty = threadIdx.x >> 6;
  for (int r = ty; r < 64; r += 4)
    tile[r][tx] = W1[(size_t)(k0 + r) * THD + n0 + tx];
  __syncthreads();
  for (int r = ty; r < 64; r += 4)
    W1t[(size_t)(n0 + r) * TFD + k0 + tx] = __float2bfloat16(tile[tx][r]);
}

// w2t[f][n] = bf16( sum_t W2[n][t*32+f]*weight[t][f] );  beff[f] = bias[f] + sum_t b2[t*32+f]*weight[t][f]
__global__ void make_w2eff(const float* __restrict__ W2, const float* __restrict__ b2,
                           const float* __restrict__ weight, const float* __restrict__ bias,
                           __hip_bfloat16* __restrict__ w2t, float* __restrict__ beff) {
  const int n = blockIdx.x * 8 + (threadIdx.x >> 5);
  const int f = threadIdx.x & 31;
  const float* wr = W2 + (size_t)n * TFD;
  float s = 0.f;
  #pragma unroll 8
  for (int t = 0; t < TT; ++t) s += wr[t * FF + f] * weight[t * FF + f];
  w2t[(size_t)f * THD + n] = __float2bfloat16(s);
  if (blockIdx.x == 0 && threadIdx.x < FF) {
    float sb = bias[f];
    for (int t = 0; t < TT; ++t) sb += b2[t * FF + f] * weight[t * FF + f];
    beff[f] = sb;
  }
}

// ---------------- main fused GEMM ----------------
// 256(batch) x 256(n_w1) tile, 8 waves (2 along n_w1 "mq" x 4 along batch "bq"),
// BK=32, TRIPLE-buffered LDS (3 x 32KB), staging 2 K-tiles ahead -> per-tile
// s_waitcnt vmcnt(4) (counted, never 0) + one raw s_barrier per K-tile.
// GEMM1 computed swapped: D[n_w1][batch] = W1t x xs^T, so the accumulator
// D-layout (col=lane&15, row=hi*4+j) IS the B-operand layout of
// mfma_f32_16x16x16_bf16 -> GEMM2 (emb^T = w2T x h^T) runs on the matrix
// pipe straight from registers (bias+relu+pack, no LDS round-trip).
// BK=32 => 64B LDS rows; fragment reads cover a contiguous 1KB per wave
// (rows 0-15 x 4 16B-chunks) = bank-conflict-optimal with NO swizzle.

__device__ inline void stage_tile(char* buf, const __hip_bfloat16* __restrict__ xs,
                                  const __hip_bfloat16* __restrict__ w1t,
                                  int b0, int n0, int k0, int wid, int l) {
  // X tile [256][32] bf16 at +0, W tile [256][32] bf16 at +16384.
  // 4 gload_lds16 per thread = one full tile (32KB) per block.
  const int row = (wid << 4) + (l >> 2);     // 0..127 within half
  const int cb  = (l & 3) * 8;               // element offset (8 bf16 = 16B)
  const __hip_bfloat16* gx0 = xs  + (size_t)(b0 + row) * TFD + k0 + cb;
  const __hip_bfloat16* gx1 = xs  + (size_t)(b0 + 128 + row) * TFD + k0 + cb;
  const __hip_bfloat16* gw0 = w1t + (size_t)(n0 + row) * TFD + k0 + cb;
  const __hip_bfloat16* gw1 = w1t + (size_t)(n0 + 128 + row) * TFD + k0 + cb;
  char* lx = buf + wid * 1024;               // wave-uniform base; HW adds lane*16
  gload_lds16(gx0, lx);
  gload_lds16(gx1, lx + 8192);
  gload_lds16(gw0, lx + 16384);
  gload_lds16(gw1, lx + 16384 + 8192);
}

__global__ __launch_bounds__(512, 2) void gemm_fused(
    const __hip_bfloat16* __restrict__ xs,    // [BATCH][TFD]
    const __hip_bfloat16* __restrict__ w1t,   // [THD][TFD]
    const float* __restrict__ b1,             // [THD]
    const __hip_bfloat16* __restrict__ w2t,   // [FF][THD] bf16
    float* __restrict__ partial)              // [8][BATCH][FF]
{
  __shared__ __align__(16) char lds[98304];   // 3 x (X 16KB + W 16KB)
  const int tid = threadIdx.x;
  const int wid = tid >> 6, l = tid & 63;
  const int mq = wid >> 2, bq = wid & 3;      // wave: n_w1-half (2) x batch-quarter (4)
  const int lo = l & 15, hi = l >> 4;
  const int strip = blockIdx.x & 7;           // consecutive blocks cycle strips -> XCD-local W reuse
  const int bt = blockIdx.x >> 3;
  const int b0 = bt * 256;

  f32x4 acc2[2][4];                           // emb^T partial: [f-frag][batch-frag]
  #pragma unroll
  for (int fi = 0; fi < 2; ++fi)
    #pragma unroll
    for (int bi = 0; bi < 4; ++bi) { f32x4 z = {0.f,0.f,0.f,0.f}; acc2[fi][bi] = z; }

  for (int s = 0; s < 4; ++s) {
    const int n0 = strip * 1024 + s * 256;

    f32x4 acc[8][4];                          // h^T frags: [n_w1-frag mi][batch-frag bi]
    #pragma unroll
    for (int mi = 0; mi < 8; ++mi)
      #pragma unroll
      for (int bi = 0; bi < 4; ++bi) { f32x4 z = {0.f,0.f,0.f,0.f}; acc[mi][bi] = z; }

    // prologue: stage tiles 0,1; wait for tile0 only (counted)
    stage_tile(lds,          xs, w1t, b0, n0, 0,  wid, l);
    stage_tile(lds + 32768,  xs, w1t, b0, n0, 32, wid, l);
    asm volatile("s_waitcnt vmcnt(4)" ::: "memory");
    __builtin_amdgcn_sched_barrier(0);
    __builtin_amdgcn_s_barrier();
    __builtin_amdgcn_sched_barrier(0);

    for (int t = 0; t < 64; ++t) {
      const char* buf = lds + (t % 3) * 32768;

      // prefetch tile t+2 into its (currently idle) buffer
      if (t < 62)
        stage_tile(lds + ((t + 2) % 3) * 32768, xs, w1t, b0, n0, (t + 2) * 32, wid, l);

      // fragment reads (conflict-free: each 16-row group = contiguous 1KB)
      bf16x8 xf[4];
      #pragma unroll
      for (int bi = 0; bi < 4; ++bi)
        xf[bi] = *(const bf16x8*)(buf + ((bq << 6) + (bi << 4) + lo) * 64 + (hi << 4));

      __builtin_amdgcn_s_setprio(1);
      #pragma unroll
      for (int mi = 0; mi < 8; ++mi) {
        const bf16x8 wf = *(const bf16x8*)(buf + 16384 + ((mq << 7) + (mi << 4) + lo) * 64 + (hi << 4));
        #pragma unroll
        for (int bi = 0; bi < 4; ++bi)
          acc[mi][bi] = __builtin_amdgcn_mfma_f32_16x16x32_bf16(wf, xf[bi], acc[mi][bi], 0, 0, 0);
      }
      __builtin_amdgcn_s_setprio(0);

      // tile boundary: ensure tile t+1 staged (all but newest 4 loads done)
      if (t < 62)       asm volatile("s_waitcnt vmcnt(4)" ::: "memory");
      else if (t == 62) asm volatile("s_waitcnt vmcnt(0)" ::: "memory");
      __builtin_amdgcn_sched_barrier(0);
      __builtin_amdgcn_s_barrier();
      __builtin_amdgcn_sched_barrier(0);
    }

    // ---- epilogue: bias+relu+pack in regs, GEMM2 on matrix pipe ----
    #pragma unroll
    for (int mi = 0; mi < 8; ++mi) {
      const int nbase = n0 + (mq << 7) + (mi << 4);
      const float4 b1v = *(const float4*)(b1 + nbase + (hi << 2));
      bf16x4 p[4];
      #pragma unroll
      for (int bi = 0; bi < 4; ++bi) {
        bf16x4 pk;
        #pragma unroll
        for (int j = 0; j < 4; ++j) {
          float v = acc[mi][bi][j] + ((const float*)&b1v)[j];
          v = v > 0.f ? v : 0.f;
          pk[j] = f32_to_bf16_bits(v);
        }
        p[bi] = pk;
      }
      bf16x4 a2[2];
      #pragma unroll
      for (int fi = 0; fi < 2; ++fi)
        a2[fi] = *(const bf16x4*)(w2t + (size_t)(fi * 16 + lo) * THD + nbase + (hi << 2));
      #pragma unroll
      for (int fi = 0; fi < 2; ++fi)
        #pragma unroll
        for (int bi = 0; bi < 4; ++bi)
          acc2[fi][bi] = mfma16x16x16_bf16(a2[fi], p[bi], acc2[fi][bi]);
    }
  }

  // ---- merge the two mq-halves via LDS, then store ----
  float* sm = (float*)lds;                    // [256][32] f32 (32KB, buffers now dead)
  if (mq == 1) {
    #pragma unroll
    for (int fi = 0; fi < 2; ++fi)
      #pragma unroll
      for (int bi = 0; bi < 4; ++bi)
        *(f32x4*)(sm + ((bq << 6) + (bi << 4) + lo) * 32 + fi * 16 + (hi << 2)) = acc2[fi][bi];
  }
  __syncthreads();
  if (mq == 0) {
    #pragma unroll
    for (int fi = 0; fi < 2; ++fi)
      #pragma unroll
      for (int bi = 0; bi < 4; ++bi) {
        f32x4 other = *(const f32x4*)(sm + ((bq << 6) + (bi << 4) + lo) * 32 + fi * 16 + (hi << 2));
        f32x4 v = acc2[fi][bi] + other;
        *(f32x4*)(partial + ((size_t)strip * BATCH + b0 + (bq << 6) + (bi << 4) + lo) * FF + fi * 16 + (hi << 2)) = v;
      }
  }
}

// out[b][f] = beff[f] + sum_c partial[c][b][f]
__global__ void reduce_partial(const float* __restrict__ partial, const float* __restrict__ beff,
                               float* __restrict__ out) {
  const int idx = blockIdx.x * 256 + threadIdx.x;
  float s = beff[idx & 31];
  #pragma unroll
  for (int c = 0; c < 8; ++c) s += partial[(size_t)c * BATCH * FF + idx];
  out[idx] = s;
}

// ---------------- launch ----------------

extern "C" void kernel_launch(void* const* d_in, const int* in_sizes, int n_in,
                              void* d_out, int out_size, void* d_ws, size_t ws_size,
                              hipStream_t stream) {
  const float* x      = (const float*)d_in[0];
  const float* W1     = (const float*)d_in[1];
  const float* b1     = (const float*)d_in[2];
  const float* W2     = (const float*)d_in[3];
  const float* b2     = (const float*)d_in[4];
  const float* weight = (const float*)d_in[5];
  const float* bias   = (const float*)d_in[6];
  const int*   sidx   = (const int*)d_in[7];

  char* ws = (char*)d_ws;
  // ws layout (bytes):
  //   xs      [16384][2048] bf16 :         0 ..  67108864
  //   w1t     [8192][2048]  bf16 :  67108864 .. 100663296
  //   w2t     [32][8192]    bf16 : 100663296 .. 101187584
  //   beff    [32]          f32  : 101187584 .. 101187712
  //   partial [8][16384][32] f32 : 101188608 .. 117965824
  __hip_bfloat16* xs   = (__hip_bfloat16*)ws;
  __hip_bfloat16* w1t  = (__hip_bfloat16*)(ws + 67108864);
  __hip_bfloat16* w2t  = (__hip_bfloat16*)(ws + 100663296);
  float*          beff = (float*)(ws + 101187584);
  float*          part = (float*)(ws + 101188608);

  hipLaunchKernelGGL(gather_cast,  dim3(BATCH),   dim3(256), 0, stream, x, sidx, xs);
  hipLaunchKernelGGL(transpose_w1, dim3(32, 128), dim3(256), 0, stream, W1, w1t);
  hipLaunchKernelGGL(make_w2eff,   dim3(1024),    dim3(256), 0, stream, W2, b2, weight, bias, w2t, beff);
  hipLaunchKernelGGL(gemm_fused,   dim3(512),     dim3(512), 0, stream, xs, w1t, b1, w2t, part);
  hipLaunchKernelGGL(reduce_partial, dim3(2048),  dim3(256), 0, stream, part, beff, (float*)d_out);
}

// Round 4
// 625.601 us; speedup vs baseline: 1.4507x; 1.0239x over previous
//
#include <hip/hip_runtime.h>
#include <hip/hip_bf16.h>

// Problem dims (fixed by reference)
#define BATCH 16384
#define TT    64
#define INF   48
#define FF    32
#define TFD   2048   // T*F   (GEMM1 K)
#define THD   8192   // T*H   (GEMM1 N)

typedef __attribute__((ext_vector_type(8))) short bf16x8;
typedef __attribute__((ext_vector_type(4))) short bf16x4;
typedef __attribute__((ext_vector_type(4))) float f32x4;

__device__ inline void gload_lds16(const void* g, void* l) {
  __builtin_amdgcn_global_load_lds((const __attribute__((address_space(1))) void*)g,
                                   (__attribute__((address_space(3))) void*)l, 16, 0, 0);
}

__device__ inline f32x4 mfma16x16x16_bf16(bf16x4 a, bf16x4 b, f32x4 c) {
#if __has_builtin(__builtin_amdgcn_mfma_f32_16x16x16bf16_1k)
  return __builtin_amdgcn_mfma_f32_16x16x16bf16_1k(a, b, c, 0, 0, 0);
#else
  asm("v_mfma_f32_16x16x16_bf16 %0, %1, %2, %0" : "+v"(c) : "v"(a), "v"(b));
  return c;
#endif
}

__device__ inline short f32_to_bf16_bits(float x) {
  __hip_bfloat16 h = __float2bfloat16(x);
  return *reinterpret_cast<short*>(&h);
}

// ---------------- prep kernels ----------------

// xs[b][t*32+f] = bf16(x[b][t*48 + sidx[f]])
__global__ void gather_cast(const float* __restrict__ x, const int* __restrict__ sidx,
                            __hip_bfloat16* __restrict__ xs) {
  const int b = blockIdx.x;
  const float* xr = x + (size_t)b * TT * INF;
  __hip_bfloat16* o = xs + (size_t)b * TFD;
  for (int j = threadIdx.x; j < TFD; j += 256) {
    const int t = j >> 5, f = j & 31;
    o[j] = __float2bfloat16(xr[t * INF + sidx[f]]);
  }
}

// W1t[n][k] = bf16(W1[k][n]);  W1: [TFD][THD] row-major
__global__ void transpose_w1(const float* __restrict__ W1, __hip_bfloat16* __restrict__ W1t) {
  __shared__ float tile[64][65];
  const int k0 = blockIdx.x * 64;
  const int n0 = blockIdx.y * 64;
  const int tx = threadIdx.x & 63, ty = threadIdx.x >> 6;
  for (int r = ty; r < 64; r += 4)
    tile[r][tx] = W1[(size_t)(k0 + r) * THD + n0 + tx];
  __syncthreads();
  for (int r = ty; r < 64; r += 4)
    W1t[(size_t)(n0 + r) * TFD + k0 + tx] = __float2bfloat16(tile[tx][r]);
}

// w2t[f][n] = bf16( sum_t W2[n][t*32+f]*weight[t][f] );  beff[f] = bias[f] + sum_t b2[t*32+f]*weight[t][f]
__global__ void make_w2eff(const float* __restrict__ W2, const float* __restrict__ b2,
                           const float* __restrict__ weight, const float* __restrict__ bias,
                           __hip_bfloat16* __restrict__ w2t, float* __restrict__ beff) {
  const int n = blockIdx.x * 8 + (threadIdx.x >> 5);
  const int f = threadIdx.x & 31;
  const float* wr = W2 + (size_t)n * TFD;
  float s = 0.f;
  #pragma unroll 8
  for (int t = 0; t < TT; ++t) s += wr[t * FF + f] * weight[t * FF + f];
  w2t[(size_t)f * THD + n] = __float2bfloat16(s);
  if (blockIdx.x == 0 && threadIdx.x < FF) {
    float sb = bias[f];
    for (int t = 0; t < TT; ++t) sb += b2[t * FF + f] * weight[t * FF + f];
    beff[f] = sb;
  }
}

// ---------------- main fused GEMM ----------------
// 256(batch) x 256(n_w1) tile, 8 waves (2 mq x 4 bq), BK=32.
// LDS layout per tile (X 16KB + W 16KB): PAIRED-ROW, 128B LDS rows:
//   LDS row r holds logical rows {2r, 2r+1}; 8 chunks of 16B with XOR
//   swizzle c' = c ^ (r&7), where c = (row&1)*4 + kchunk. Staged via
//   linear LDS dest + inverse-swizzled global source (global_load_lds
//   writes base+lane*16 only); read-side XOR folds to a lane-constant
//   byte offset. 16-lane read phases hit all 8 bank-groups exactly
//   twice = 2-way = free (the 64B-row layout was ~8-way).
// 4-deep buffers (4 x 32KB = 128KB), staging 3 tiles ahead ->
// per-iter s_waitcnt vmcnt(8) waits on loads issued 3 iters (~2.4K cyc)
// earlier => near-zero wait. vmcnt(4)/(0) only in the K-loop tail.
// GEMM1 swapped (D[n][batch]) so GEMM2 runs on the matrix pipe straight
// from the accumulators (bias+relu+pack, no LDS round-trip).

__device__ inline void stage_tile(char* buf, const __hip_bfloat16* __restrict__ xs,
                                  const __hip_bfloat16* __restrict__ w1t,
                                  int b0, int n0, int k0, int wid, int l) {
  // Linear LDS dest: wave wid covers bytes [wid*1024, wid*1024+1KB) per round.
  // lane l -> ldsrow sub = l>>3 (within wave's 8 rows), chunk slot c' = l&7.
  // Source chunk c = c' ^ (ldsrow&7); ldsrow&7 == sub (wid*8 = 0 mod 8).
  const int sub = l >> 3;
  const int c   = (l & 7) ^ sub;
  const int h   = c >> 2, kc = c & 3;
  const int kofs = k0 + kc * 8;
  const int r0 = wid * 8 + sub;              // round-0 ldsrow
  const __hip_bfloat16* gx0 = xs  + (size_t)(b0 + 2 * r0 + h) * TFD + kofs;
  const __hip_bfloat16* gx1 = xs  + (size_t)(b0 + 128 + 2 * r0 + h) * TFD + kofs;
  const __hip_bfloat16* gw0 = w1t + (size_t)(n0 + 2 * r0 + h) * TFD + kofs;
  const __hip_bfloat16* gw1 = w1t + (size_t)(n0 + 128 + 2 * r0 + h) * TFD + kofs;
  char* lx = buf + wid * 1024;               // wave-uniform base; HW adds lane*16
  gload_lds16(gx0, lx);
  gload_lds16(gx1, lx + 8192);
  gload_lds16(gw0, lx + 16384);
  gload_lds16(gw1, lx + 16384 + 8192);
}

__global__ __launch_bounds__(512, 2) void gemm_fused(
    const __hip_bfloat16* __restrict__ xs,    // [BATCH][TFD]
    const __hip_bfloat16* __restrict__ w1t,   // [THD][TFD]
    const float* __restrict__ b1,             // [THD]
    const __hip_bfloat16* __restrict__ w2t,   // [FF][THD] bf16
    float* __restrict__ partial)              // [8][BATCH][FF]
{
  __shared__ __align__(16) char lds[131072];  // 4 x (X 16KB + W 16KB)
  const int tid = threadIdx.x;
  const int wid = tid >> 6, l = tid & 63;
  const int mq = wid >> 2, bq = wid & 3;      // wave: n_w1-half (2) x batch-quarter (4)
  const int lo = l & 15, hi = l >> 4;         // frag col / k-chunk
  const int rl = lo >> 1;                     // paired-row index within 16
  const int cofs = (((((lo & 1) << 2) | hi) ^ (rl & 7)) << 4);  // lane-const swizzled chunk byte
  const int strip = blockIdx.x & 7;           // strip == XCD (default %8 mapping) -> W slice L2-resident
  const int bt = blockIdx.x >> 3;
  const int b0 = bt * 256;

  // lane-constant fragment base offsets
  const int xbase = ((bq << 5) + rl) * 128 + cofs;            // + (bi<<3)*128
  const int wbase = 16384 + ((mq << 6) + rl) * 128 + cofs;    // + (mi<<3)*128

  f32x4 acc2[2][4];                           // emb^T partial: [f-frag][batch-frag]
  #pragma unroll
  for (int fi = 0; fi < 2; ++fi)
    #pragma unroll
    for (int bi = 0; bi < 4; ++bi) { f32x4 z = {0.f,0.f,0.f,0.f}; acc2[fi][bi] = z; }

  for (int s = 0; s < 4; ++s) {
    const int n0 = strip * 1024 + s * 256;

    f32x4 acc[8][4];                          // h^T frags: [n_w1-frag mi][batch-frag bi]
    #pragma unroll
    for (int mi = 0; mi < 8; ++mi)
      #pragma unroll
      for (int bi = 0; bi < 4; ++bi) { f32x4 z = {0.f,0.f,0.f,0.f}; acc[mi][bi] = z; }

    // prologue: stage tiles 0,1,2; wait for tile0 only (8 = tiles 1,2 in flight)
    stage_tile(lds,          xs, w1t, b0, n0, 0,  wid, l);
    stage_tile(lds + 32768,  xs, w1t, b0, n0, 32, wid, l);
    stage_tile(lds + 65536,  xs, w1t, b0, n0, 64, wid, l);
    asm volatile("s_waitcnt vmcnt(8)" ::: "memory");
    __builtin_amdgcn_sched_barrier(0);
    __builtin_amdgcn_s_barrier();
    __builtin_amdgcn_sched_barrier(0);

    for (int t = 0; t < 64; ++t) {
      const char* buf = lds + (size_t)(t & 3) * 32768;

      // prefetch tile t+3 into its (idle: held t-1, consumed) buffer
      if (t < 61)
        stage_tile(lds + (size_t)((t + 3) & 3) * 32768, xs, w1t, b0, n0, (t + 3) * 32, wid, l);

      // fragment reads (swizzled; 2-way bank aliasing = free)
      bf16x8 xf[4];
      #pragma unroll
      for (int bi = 0; bi < 4; ++bi)
        xf[bi] = *(const bf16x8*)(buf + xbase + (bi << 3) * 128);

      __builtin_amdgcn_s_setprio(1);
      #pragma unroll
      for (int mi = 0; mi < 8; ++mi) {
        const bf16x8 wf = *(const bf16x8*)(buf + wbase + (mi << 3) * 128);
        #pragma unroll
        for (int bi = 0; bi < 4; ++bi)
          acc[mi][bi] = __builtin_amdgcn_mfma_f32_16x16x32_bf16(wf, xf[bi], acc[mi][bi], 0, 0, 0);
      }
      __builtin_amdgcn_s_setprio(0);

      // tile boundary: ensure tile t+1 staged; keep 2 tiles (8 loads) in flight
      if (t < 61)       asm volatile("s_waitcnt vmcnt(8)" ::: "memory");
      else if (t == 61) asm volatile("s_waitcnt vmcnt(4)" ::: "memory");
      else if (t == 62) asm volatile("s_waitcnt vmcnt(0)" ::: "memory");
      __builtin_amdgcn_sched_barrier(0);
      __builtin_amdgcn_s_barrier();
      __builtin_amdgcn_sched_barrier(0);
    }

    // ---- epilogue: bias+relu+pack in regs, GEMM2 on matrix pipe ----
    #pragma unroll
    for (int mi = 0; mi < 8; ++mi) {
      const int nbase = n0 + (mq << 7) + (mi << 4);
      const float4 b1v = *(const float4*)(b1 + nbase + (hi << 2));
      bf16x4 p[4];
      #pragma unroll
      for (int bi = 0; bi < 4; ++bi) {
        bf16x4 pk;
        #pragma unroll
        for (int j = 0; j < 4; ++j) {
          float v = acc[mi][bi][j] + ((const float*)&b1v)[j];
          v = v > 0.f ? v : 0.f;
          pk[j] = f32_to_bf16_bits(v);
        }
        p[bi] = pk;
      }
      bf16x4 a2[2];
      #pragma unroll
      for (int fi = 0; fi < 2; ++fi)
        a2[fi] = *(const bf16x4*)(w2t + (size_t)(fi * 16 + lo) * THD + nbase + (hi << 2));
      #pragma unroll
      for (int fi = 0; fi < 2; ++fi)
        #pragma unroll
        for (int bi = 0; bi < 4; ++bi)
          acc2[fi][bi] = mfma16x16x16_bf16(a2[fi], p[bi], acc2[fi][bi]);
    }
  }

  // ---- merge the two mq-halves via LDS, then store ----
  float* sm = (float*)lds;                    // [256][32] f32 (32KB; buffers dead)
  if (mq == 1) {
    #pragma unroll
    for (int fi = 0; fi < 2; ++fi)
      #pragma unroll
      for (int bi = 0; bi < 4; ++bi)
        *(f32x4*)(sm + ((bq << 6) + (bi << 4) + lo) * 32 + fi * 16 + (hi << 2)) = acc2[fi][bi];
  }
  __syncthreads();
  if (mq == 0) {
    #pragma unroll
    for (int fi = 0; fi < 2; ++fi)
      #pragma unroll
      for (int bi = 0; bi < 4; ++bi) {
        f32x4 other = *(const f32x4*)(sm + ((bq << 6) + (bi << 4) + lo) * 32 + fi * 16 + (hi << 2));
        f32x4 v = acc2[fi][bi] + other;
        *(f32x4*)(partial + ((size_t)strip * BATCH + b0 + (bq << 6) + (bi << 4) + lo) * FF + fi * 16 + (hi << 2)) = v;
      }
  }
}

// out[b][f] = beff[f] + sum_c partial[c][b][f]
__global__ void reduce_partial(const float* __restrict__ partial, const float* __restrict__ beff,
                               float* __restrict__ out) {
  const int idx = blockIdx.x * 256 + threadIdx.x;
  float s = beff[idx & 31];
  #pragma unroll
  for (int c = 0; c < 8; ++c) s += partial[(size_t)c * BATCH * FF + idx];
  out[idx] = s;
}

// ---------------- launch ----------------

extern "C" void kernel_launch(void* const* d_in, const int* in_sizes, int n_in,
                              void* d_out, int out_size, void* d_ws, size_t ws_size,
                              hipStream_t stream) {
  const float* x      = (const float*)d_in[0];
  const float* W1     = (const float*)d_in[1];
  const float* b1     = (const float*)d_in[2];
  const float* W2     = (const float*)d_in[3];
  const float* b2     = (const float*)d_in[4];
  const float* weight = (const float*)d_in[5];
  const float* bias   = (const float*)d_in[6];
  const int*   sidx   = (const int*)d_in[7];

  char* ws = (char*)d_ws;
  // ws layout (bytes):
  //   xs      [16384][2048] bf16 :         0 ..  67108864
  //   w1t     [8192][2048]  bf16 :  67108864 .. 100663296
  //   w2t     [32][8192]    bf16 : 100663296 .. 101187584
  //   beff    [32]          f32  : 101187584 .. 101187712
  //   partial [8][16384][32] f32 : 101188608 .. 117965824
  __hip_bfloat16* xs   = (__hip_bfloat16*)ws;
  __hip_bfloat16* w1t  = (__hip_bfloat16*)(ws + 67108864);
  __hip_bfloat16* w2t  = (__hip_bfloat16*)(ws + 100663296);
  float*          beff = (float*)(ws + 101187584);
  float*          part = (float*)(ws + 101188608);

  hipLaunchKernelGGL(gather_cast,  dim3(BATCH),   dim3(256), 0, stream, x, sidx, xs);
  hipLaunchKernelGGL(transpose_w1, dim3(32, 128), dim3(256), 0, stream, W1, w1t);
  hipLaunchKernelGGL(make_w2eff,   dim3(1024),    dim3(256), 0, stream, W2, b2, weight, bias, w2t, beff);
  hipLaunchKernelGGL(gemm_fused,   dim3(512),     dim3(512), 0, stream, xs, w1t, b1, w2t, part);
  hipLaunchKernelGGL(reduce_partial, dim3(2048),  dim3(256), 0, stream, part, beff, (float*)d_out);
}